// Round 14
// baseline (103.101 us; speedup 1.0000x reference)
//
#include <hip/hip_runtime.h>
#include <hip/hip_bf16.h>

typedef __attribute__((ext_vector_type(8))) __bf16 bf16x8;
typedef __attribute__((ext_vector_type(4))) __bf16 bf16x4;
typedef __attribute__((ext_vector_type(4))) float  f32x4;
typedef __attribute__((ext_vector_type(16))) float f32x16;

#define L2E 1.44269504088896340736f

static __device__ __forceinline__ f32x4 mfma16(bf16x8 a, bf16x8 b, f32x4 c) {
    return __builtin_amdgcn_mfma_f32_16x16x32_bf16(a, b, c, 0, 0, 0);
}
static __device__ __forceinline__ f32x16 mfma32(bf16x8 a, bf16x8 b, f32x16 c) {
    return __builtin_amdgcn_mfma_f32_32x32x16_bf16(a, b, c, 0, 0, 0);
}

#define GLOAD_LDS16(gsrc, ldst)                                                \
    __builtin_amdgcn_global_load_lds(                                          \
        (const __attribute__((address_space(1))) unsigned int*)(gsrc),         \
        (__attribute__((address_space(3))) unsigned int*)(ldst), 16, 0, 0)

// ---------------- Weight prep: th_w, ph_w, g_w [128x256], W_w [256x128] -> bf16 -------------
__global__ __launch_bounds__(256) void prep_w(
    const float* __restrict__ thw, const float* __restrict__ phw,
    const float* __restrict__ gw,  const float* __restrict__ Ww,
    __bf16* __restrict__ wbf)
{
    const int idx  = blockIdx.x * 256 + threadIdx.x;
    const int base = idx * 4;
    const float* src = (base < 32768) ? thw : (base < 65536) ? phw
                     : (base < 98304) ? gw  : Ww;
    const int off = base & 32767;
    f32x4 v = *reinterpret_cast<const f32x4*>(src + off);
    bf16x4 o;
    #pragma unroll
    for (int i = 0; i < 4; ++i) o[i] = (__bf16)v[i];
    *reinterpret_cast<bf16x4*>(wbf + base) = o;
}

// ---------------- Fused projection p: x [B,C,N] f32 -> theta/phi [B,N,128] | gBlk -----------
// Grid (64 n-tiles, 3 p, 4 b); LDS 64KB -> 2 blocks/CU. Each block stages x f32 ->
// LDS transpose (TF aliased over WL) -> swizzled bf16 XA, then two 64-o WL halves:
// stage (gload_lds, pre-swizzled wbf) + MFMA. p==2 epilogue transposes into gBlk.
__global__ __launch_bounds__(256, 2) void proj_fused(
    const float* __restrict__ x, const __bf16* __restrict__ wbf,
    const float* __restrict__ bth, const float* __restrict__ bph,
    const float* __restrict__ bg,
    __bf16* __restrict__ thetaT, __bf16* __restrict__ phiT, __bf16* __restrict__ gBlk)
{
    const int p    = blockIdx.y;
    const int b    = blockIdx.z;
    const int n0   = blockIdx.x * 64;
    const int w    = threadIdx.x >> 6;
    const int lane = threadIdx.x & 63;
    const int lo   = lane & 15;
    const int hi   = lane >> 4;
    const int tr   = threadIdx.x >> 4;      // 0..15
    const int tc   = threadIdx.x & 15;      // 0..15

    __shared__ alignas(16) __bf16 XA[64 * 256];    // 32KB; reused as T[128][66] in p==2 epi
    __shared__ alignas(16) __bf16 WL[64 * 256];    // 32KB half-W; TF aliases its first 16.6KB
    float* TF = (float*)&WL[0];                    // TF[64][65] f32, x-stage phase only

    // ---- stage x -> XA (transposed, bf16, swizzled), 4 chunks of 64 channels ----
    #pragma unroll 1
    for (int cb = 0; cb < 4; ++cb) {
        if (cb) __syncthreads();
        #pragma unroll
        for (int k = 0; k < 4; ++k) {
            const int cl = k * 16 + tr;
            f32x4 v = *reinterpret_cast<const f32x4*>(
                x + ((size_t)b * 256 + cb * 64 + cl) * 4096 + n0 + tc * 4);
            #pragma unroll
            for (int i = 0; i < 4; ++i) TF[cl * 65 + tc * 4 + i] = v[i];
        }
        __syncthreads();
        #pragma unroll
        for (int k = 0; k < 4; ++k) {
            const int nl = k * 16 + tr;
            bf16x4 v;
            #pragma unroll
            for (int i = 0; i < 4; ++i) v[i] = (__bf16)TF[(tc * 4 + i) * 65 + nl];
            const int dst = nl * 512 + ((cb * 128 + tc * 8) ^ ((nl & 7) << 4));
            *reinterpret_cast<bf16x4*>((char*)XA + dst) = v;
        }
    }
    __syncthreads();

    // ---- two 64-o halves of this projection's weights ----
    const __bf16* wsrc = wbf + p * 32768;
    f32x4 C[2][4];
    #pragma unroll
    for (int hh = 0; hh < 2; ++hh)
        #pragma unroll
        for (int cc = 0; cc < 4; ++cc) C[hh][cc] = f32x4{0.f, 0.f, 0.f, 0.f};

    #pragma unroll 1
    for (int hh = 0; hh < 2; ++hh) {
        if (hh) __syncthreads();            // WL WAR vs previous half's MFMA reads
        #pragma unroll
        for (int u = 0; u < 8; ++u) {
            const int chunk = (w * 8 + u) * 64 + lane;   // 0..2047
            const int row   = chunk >> 5;                // local o row 0..63
            const int jb    = (chunk & 31) * 16;
            const int sb    = row * 512 + (jb ^ ((row & 7) << 4));
            GLOAD_LDS16(wsrc + hh * 16384 + (sb >> 1), &WL[(w * 8 + u) * 512]);
        }
        __syncthreads();

        const int arow = w * 16 + lo;       // wave owns n-tile w
        #pragma unroll
        for (int kb = 0; kb < 8; ++kb) {
            const int koff = kb * 64 + hi * 16;
            bf16x8 a = *reinterpret_cast<const bf16x8*>(
                (const char*)XA + arow * 512 + (koff ^ ((arow & 7) << 4)));
            bf16x8 bb[4];
            #pragma unroll
            for (int cc = 0; cc < 4; ++cc) {
                const int o = cc * 16 + lo;
                bb[cc] = *reinterpret_cast<const bf16x8*>(
                    (const char*)WL + o * 512 + (koff ^ ((o & 7) << 4)));
            }
            #pragma unroll
            for (int cc = 0; cc < 4; ++cc) C[hh][cc] = mfma16(a, bb[cc], C[hh][cc]);
        }
    }

    const float* bias = (p == 0) ? bth : (p == 1) ? bph : bg;
    if (p < 2) {
        __bf16* out = (p == 0) ? thetaT : phiT;
        const int nbase = n0 + w * 16;
        #pragma unroll
        for (int hh = 0; hh < 2; ++hh)
            #pragma unroll
            for (int cc = 0; cc < 4; ++cc) {
                const int o  = hh * 64 + cc * 16 + lo;
                const float bv = bias[o];
                #pragma unroll
                for (int r = 0; r < 4; ++r)
                    out[((size_t)b * 4096 + nbase + 4 * hi + r) * 128 + o] =
                        (__bf16)(C[hh][cc][r] + bv);
            }
    } else {
        // transpose via LDS (XA dead), write gBlk with the 4-wide m-group permutation
        __syncthreads();
        __bf16* T = &XA[0];                 // T[o][66], 128 x 66 = 16.9KB
        #pragma unroll
        for (int hh = 0; hh < 2; ++hh)
            #pragma unroll
            for (int cc = 0; cc < 4; ++cc) {
                const int o  = hh * 64 + cc * 16 + lo;
                const float bv = bias[o];
                #pragma unroll
                for (int r = 0; r < 4; ++r)
                    T[o * 66 + w * 16 + 4 * hi + r] = (__bf16)(C[hh][cc][r] + bv);
            }
        __syncthreads();
        #pragma unroll
        for (int q8 = 0; q8 < 8; ++q8) {
            const int qid = q8 * 256 + threadIdx.x;   // 0..2047
            const int c   = qid >> 4;                 // channel 0..127
            const int nl  = (qid & 15) * 4;
            const int n   = n0 + nl;
            const int mt  = n >> 5;
            const int mm  = n & 31;
            const int g   = mm >> 2;
            const int gp  = (g & 4) | ((g & 1) << 1) | ((g >> 1) & 1);
            bf16x4 v;
            #pragma unroll
            for (int i = 0; i < 4; ++i) v[i] = T[c * 66 + nl + i];
            *reinterpret_cast<bf16x4*>(
                gBlk + (((size_t)(b * 128 + mt)) * 128 + c) * 32 + (gp << 2)) = v;
        }
    }
}

// ---------------- Flash attention: round-9 winner (45.5us), unchanged -----------------------
template<int NCH>
__global__ __launch_bounds__(256, 3) void attn_kernel(
    const __bf16* __restrict__ thetaT, const __bf16* __restrict__ phiT,
    const __bf16* __restrict__ gBlk, __bf16* __restrict__ yPart,
    float* __restrict__ lPart)
{
    constexpr int SH = (NCH == 8) ? 3 : 2;
    constexpr int NT = (4096 / NCH) / 32;
    const int bid   = blockIdx.x;
    const int chunk = bid & (NCH - 1);
    const int qb    = (bid >> SH) & 31;
    const int b     = bid >> (SH + 5);
    const int w     = threadIdx.x >> 6;
    const int lane  = threadIdx.x & 63;
    const int l31   = lane & 31;
    const int h2    = lane >> 5;
    const int Q0    = qb * 128 + w * 32;
    const int kvbase = chunk * (4096 / NCH);

    __shared__ alignas(16) __bf16 Kt[3][32 * 128];
    __shared__ alignas(16) __bf16 Vt[3][128 * 32];

    bf16x8 qf[8];
    {
        const __bf16* qrow = thetaT + ((size_t)b * 4096 + Q0 + l31) * 128 + h2 * 8;
        #pragma unroll
        for (int ks = 0; ks < 8; ++ks)
            qf[ks] = *reinterpret_cast<const bf16x8*>(qrow + ks * 16);
    }

    f32x16 yacc[4];
    #pragma unroll
    for (int ct = 0; ct < 4; ++ct)
        #pragma unroll
        for (int r = 0; r < 16; ++r) yacc[ct][r] = 0.f;
    float ylrun = 0.f;

    const __bf16* phiB   = phiT + (size_t)b * 4096 * 128;
    const __bf16* gBlk_b = gBlk + (size_t)b * 128 * 4096;

    auto stage = [&](int buf, int t) {
        const int kv = kvbase + t * 32;
        #pragma unroll
        for (int u = 0; u < 2; ++u) {
            const int ii   = w + u * 4;
            const int mrow = ii * 4 + (lane >> 4);
            const int cbl  = ((lane & 15) * 16) ^ ((mrow & 7) << 4);
            const __bf16* src = phiB + ((size_t)(kv + mrow) << 7) + (cbl >> 1);
            GLOAD_LDS16(src, &Kt[buf][ii * 512]);
        }
        const __bf16* vtile = gBlk_b + ((size_t)(kv >> 5) << 12);
        #pragma unroll
        for (int u = 0; u < 2; ++u) {
            const int jj = w + u * 4;
            const int ch = jj * 64 + lane;
            const int c  = ch >> 2;
            const int h  = (ch & 3) ^ ((c >> 1) & 3);
            const __bf16* src = vtile + c * 32 + h * 8;
            GLOAD_LDS16(src, &Vt[buf][jj * 512]);
        }
    };

    stage(0, 0);
    stage(1, 1);

    int ia = 0, ib = 1, ic = 2;
    const int sw = (l31 >> 1) & 3;

    #pragma unroll 1
    for (int t = 0; t < NT; ++t) {
        if (t < NT - 2) {
            stage(ic, t + 2);
            asm volatile("s_waitcnt vmcnt(8)" ::: "memory");
        } else if (t == NT - 2) {
            asm volatile("s_waitcnt vmcnt(4)" ::: "memory");
        } else {
            asm volatile("s_waitcnt vmcnt(0)" ::: "memory");
        }
        __builtin_amdgcn_s_barrier();
        __builtin_amdgcn_sched_barrier(0);

        const char* Kb = (const char*)&Kt[ia][0];
        const char* Vb = (const char*)&Vt[ia][0];

        f32x16 S;
        #pragma unroll
        for (int r = 0; r < 16; ++r) S[r] = 0.f;
        #pragma unroll
        for (int ks = 0; ks < 8; ++ks) {
            bf16x8 ka = *reinterpret_cast<const bf16x8*>(
                Kb + l31 * 256 + ((ks * 32 + h2 * 16) ^ ((l31 & 7) << 4)));
            S = mfma32(ka, qf[ks], S);
        }

        float p[16];
        #pragma unroll
        for (int r = 0; r < 16; ++r) p[r] = __builtin_amdgcn_exp2f(S[r] * L2E);
        float ls = 0.f;
        #pragma unroll
        for (int r = 0; r < 16; ++r) ls += p[r];
        ylrun += ls;
        bf16x8 pa0, pa1;
        #pragma unroll
        for (int e = 0; e < 8; ++e) { pa0[e] = (__bf16)p[e]; pa1[e] = (__bf16)p[8 + e]; }

        #pragma unroll
        for (int ct = 0; ct < 4; ++ct) {
            const int vrow = (ct * 32 + l31) * 64;
            bf16x8 v0 = *reinterpret_cast<const bf16x8*>(Vb + vrow + ((h2 ^ sw) << 4));
            bf16x8 v1 = *reinterpret_cast<const bf16x8*>(Vb + vrow + (((2 + h2) ^ sw) << 4));
            yacc[ct] = mfma32(pa0, v0, yacc[ct]);
            yacc[ct] = mfma32(pa1, v1, yacc[ct]);
        }

        asm volatile("" ::: "memory");
        __builtin_amdgcn_s_barrier();
        __builtin_amdgcn_sched_barrier(0);
        const int tmp = ia; ia = ib; ib = ic; ic = tmp;
    }

    const float ylt = ylrun + __shfl_xor(ylrun, 32);
    const int bc = chunk * 4 + b;
    #pragma unroll
    for (int ct = 0; ct < 4; ++ct)
        #pragma unroll
        for (int r = 0; r < 16; ++r) {
            const int q = Q0 + (r & 3) + 8 * (r >> 2) + 4 * h2;
            yPart[((size_t)bc * 4096 + q) * 128 + ct * 32 + l31] = (__bf16)yacc[ct][r];
        }
    if (h2 == 0)
        lPart[(size_t)bc * 4096 + Q0 + l31] = ylt;
}

// ---------------- wy MFMA: fused chunk-merge + inline linv + deferred normalize + BN stats --
template<int NC>
__global__ __launch_bounds__(256, 1) void wy_mfma(
    const __bf16* __restrict__ yPart, const float* __restrict__ lPart,
    const __bf16* __restrict__ wW, const float* __restrict__ Wb,
    __bf16* __restrict__ Wy, float* __restrict__ pSQ)
{
    const int b    = blockIdx.y;
    const int n0   = blockIdx.x * 64;
    const int w    = threadIdx.x >> 6;
    const int lane = threadIdx.x & 63;
    const int lo   = lane & 15;
    const int hi   = lane >> 4;

    __shared__ alignas(16) __bf16 YL[64 * 128];
    __shared__ alignas(16) __bf16 WL[256 * 128];

    #pragma unroll
    for (int u = 0; u < 16; ++u) {
        const int chunk = (w * 16 + u) * 64 + lane;
        const int row   = chunk >> 4;
        const int jb    = (chunk & 15) * 16;
        const int sb    = row * 256 + (jb ^ ((row & 7) << 4));
        GLOAD_LDS16(wW + (sb >> 1), &WL[(w * 16 + u) * 512]);
    }
    #pragma unroll
    for (int u = 0; u < 4; ++u) {
        const int ch   = u * 256 + threadIdx.x;
        const int row  = ch >> 4;
        const int col8 = ch & 15;
        float acc8[8];
        #pragma unroll
        for (int e = 0; e < 8; ++e) acc8[e] = 0.f;
        #pragma unroll
        for (int c = 0; c < NC; ++c) {
            bf16x8 v = *reinterpret_cast<const bf16x8*>(
                yPart + ((size_t)(c * 4 + b) * 4096 + n0 + row) * 128 + col8 * 8);
            #pragma unroll
            for (int e = 0; e < 8; ++e) acc8[e] += (float)v[e];
        }
        bf16x8 o8;
        #pragma unroll
        for (int e = 0; e < 8; ++e) o8[e] = (__bf16)acc8[e];
        *reinterpret_cast<bf16x8*>(
            (char*)YL + row * 256 + ((col8 * 16) ^ ((row & 7) << 4))) = o8;
    }
    __syncthreads();

    f32x4 C[4][4];
    #pragma unroll
    for (int og = 0; og < 4; ++og)
        #pragma unroll
        for (int ct = 0; ct < 4; ++ct) C[og][ct] = f32x4{0.f, 0.f, 0.f, 0.f};

    #pragma unroll
    for (int kb = 0; kb < 4; ++kb) {
        const int koff = kb * 64 + hi * 16;
        bf16x8 a[4], bb[4];
        #pragma unroll
        for (int og = 0; og < 4; ++og) {
            const int o = w * 64 + og * 16 + lo;
            a[og] = *reinterpret_cast<const bf16x8*>(
                (const char*)WL + o * 256 + (koff ^ ((o & 7) << 4)));
        }
        #pragma unroll
        for (int ct = 0; ct < 4; ++ct) {
            const int nl = ct * 16 + lo;
            bb[ct] = *reinterpret_cast<const bf16x8*>(
                (const char*)YL + nl * 256 + (koff ^ ((nl & 7) << 4)));
        }
        #pragma unroll
        for (int og = 0; og < 4; ++og)
            #pragma unroll
            for (int ct = 0; ct < 4; ++ct)
                C[og][ct] = mfma16(a[og], bb[ct], C[og][ct]);
    }

    // inline linv: 1 / sum_c lPart[c][b*4096 + n]
    float linvv[4];
    #pragma unroll
    for (int ct = 0; ct < 4; ++ct) {
        const int n = b * 4096 + n0 + ct * 16 + lo;
        float s = 0.f;
        #pragma unroll
        for (int c = 0; c < NC; ++c) s += lPart[(size_t)c * 16384 + n];
        linvv[ct] = 1.0f / s;
    }

    const int blk = blockIdx.y * 64 + blockIdx.x;   // 0..255
    #pragma unroll
    for (int og = 0; og < 4; ++og)
        #pragma unroll
        for (int r = 0; r < 4; ++r) {
            const int o  = w * 64 + og * 16 + 4 * hi + r;
            const float bv = Wb[o];
            float s = 0.f, q = 0.f;
            #pragma unroll
            for (int ct = 0; ct < 4; ++ct) {
                const float v = C[og][ct][r] * linvv[ct] + bv;
                Wy[((size_t)b * 256 + o) * 4096 + n0 + ct * 16 + lo] = (__bf16)v;
                s += v; q += v * v;
            }
            #pragma unroll
            for (int off = 1; off <= 8; off <<= 1) {
                s += __shfl_xor(s, off);
                q += __shfl_xor(q, off);
            }
            if (lo == 0) {
                pSQ[blk * 256 + o]         = s;
                pSQ[65536 + blk * 256 + o] = q;
            }
        }
}

// ---------------- stats finalize: reduce 256 partials per channel ---------------------------
__global__ __launch_bounds__(256) void stats_finalize(
    const float* __restrict__ pSQ, const float* __restrict__ gamma,
    const float* __restrict__ beta, float* __restrict__ stats)
{
    const int o = blockIdx.x;
    const int t = threadIdx.x;
    float s = pSQ[t * 256 + o];
    float q = pSQ[65536 + t * 256 + o];
    #pragma unroll
    for (int off = 32; off >= 1; off >>= 1) {
        s += __shfl_down(s, off);
        q += __shfl_down(q, off);
    }
    __shared__ float red[8];
    const int wid = t >> 6;
    if ((t & 63) == 0) { red[wid] = s; red[4 + wid] = q; }
    __syncthreads();
    if (t == 0) {
        const float S = red[0] + red[1] + red[2] + red[3];
        const float Q = red[4] + red[5] + red[6] + red[7];
        const float mean = S * (1.f / 16384.f);
        const float var  = Q * (1.f / 16384.f) - mean * mean;
        const float scl  = gamma[o] * rsqrtf(var + 1e-5f);
        stats[o]       = scl;
        stats[256 + o] = beta[o] - mean * scl;
    }
}

// ---------------- out = Wy(bf16)*scale + shift + x ------------------------------------------
__global__ __launch_bounds__(256) void final_kernel(
    const __bf16* __restrict__ Wy, const float* __restrict__ x,
    const float* __restrict__ stats, float* __restrict__ out)
{
    const int idx = blockIdx.x * 256 + threadIdx.x;
    const int o   = (idx >> 10) & 255;
    bf16x4 wyb = *reinterpret_cast<const bf16x4*>(Wy + (size_t)idx * 4);
    f32x4 xv = *reinterpret_cast<const f32x4*>(x + (size_t)idx * 4);
    const float scl = stats[o], sh = stats[256 + o];
    f32x4 res;
    #pragma unroll
    for (int i = 0; i < 4; ++i) res[i] = (float)wyb[i] * scl + sh + xv[i];
    *reinterpret_cast<f32x4*>(out + (size_t)idx * 4) = res;
}

extern "C" void kernel_launch(void* const* d_in, const int* in_sizes, int n_in,
                              void* d_out, int out_size, void* d_ws, size_t ws_size,
                              hipStream_t stream)
{
    const float* x    = (const float*)d_in[0];
    const float* g_w  = (const float*)d_in[1];
    const float* g_b  = (const float*)d_in[2];
    const float* th_w = (const float*)d_in[3];
    const float* th_b = (const float*)d_in[4];
    const float* ph_w = (const float*)d_in[5];
    const float* ph_b = (const float*)d_in[6];
    const float* W_w  = (const float*)d_in[7];
    const float* W_b  = (const float*)d_in[8];
    const float* bn_g = (const float*)d_in[9];
    const float* bn_b = (const float*)d_in[10];
    float* out = (float*)d_out;

    // Workspace phases:
    //   proj:  thetaT@0 (4M) | phiT@4M (4M) | gBlk@8M (4M)
    //   attn:  reads thetaT/phiT/gBlk; yPart@12M (32M big / 16M small)
    //   wy:    reads yPart+lPart; Wy(bf16)@0 (8M over dead thetaT/phiT); pSQ@8M (512K)
    //   tail:  lPart | wbf | stats @44M (big) / @28M (small)
    char* ws = (char*)d_ws;
    const size_t MB = 1u << 20;
    __bf16* thetaT = (__bf16*)(ws);
    __bf16* phiT   = (__bf16*)(ws + 4 * MB);
    __bf16* gBlk   = (__bf16*)(ws + 8 * MB);
    __bf16* yPart  = (__bf16*)(ws + 12 * MB);
    __bf16* Wy     = (__bf16*)(ws);
    float*  pSQ    = (float*) (ws + 8 * MB);

    const bool big = ws_size >= 46926848ull;
    const size_t tail = big ? 44 * MB : 28 * MB;
    float*  lPart = (float*) (ws + tail);
    __bf16* wbf   = (__bf16*)(ws + tail + (big ? 524288 : 262144));
    float*  stats = (float*) (ws + tail + (big ? 786432 : 524288));

    prep_w<<<dim3(128), 256, 0, stream>>>(th_w, ph_w, g_w, W_w, wbf);
    proj_fused<<<dim3(64, 3, 4), 256, 0, stream>>>(
        x, wbf, th_b, ph_b, g_b, thetaT, phiT, gBlk);
    if (big) {
        attn_kernel<8><<<dim3(1024), 256, 0, stream>>>(thetaT, phiT, gBlk, yPart, lPart);
        wy_mfma<8><<<dim3(64, 4), 256, 0, stream>>>(yPart, lPart, wbf + 98304, W_b, Wy, pSQ);
    } else {
        attn_kernel<4><<<dim3(512), 256, 0, stream>>>(thetaT, phiT, gBlk, yPart, lPart);
        wy_mfma<4><<<dim3(64, 4), 256, 0, stream>>>(yPart, lPart, wbf + 98304, W_b, Wy, pSQ);
    }
    stats_finalize<<<dim3(256), 256, 0, stream>>>(pSQ, bn_g, bn_b, stats);
    final_kernel<<<dim3(4096), 256, 0, stream>>>(Wy, x, stats, out);
}

// Round 15
// 89.947 us; speedup vs baseline: 1.1462x; 1.1462x over previous
//
#include <hip/hip_runtime.h>
#include <hip/hip_bf16.h>

typedef __attribute__((ext_vector_type(8))) __bf16 bf16x8;
typedef __attribute__((ext_vector_type(4))) __bf16 bf16x4;
typedef __attribute__((ext_vector_type(4))) float  f32x4;
typedef __attribute__((ext_vector_type(16))) float f32x16;

#define L2E 1.44269504088896340736f

static __device__ __forceinline__ f32x4 mfma16(bf16x8 a, bf16x8 b, f32x4 c) {
    return __builtin_amdgcn_mfma_f32_16x16x32_bf16(a, b, c, 0, 0, 0);
}
static __device__ __forceinline__ f32x16 mfma32(bf16x8 a, bf16x8 b, f32x16 c) {
    return __builtin_amdgcn_mfma_f32_32x32x16_bf16(a, b, c, 0, 0, 0);
}

#define GLOAD_LDS16(gsrc, ldst)                                                \
    __builtin_amdgcn_global_load_lds(                                          \
        (const __attribute__((address_space(1))) unsigned int*)(gsrc),         \
        (__attribute__((address_space(3))) unsigned int*)(ldst), 16, 0, 0)

// ---------------- Weight prep: th_w, ph_w, g_w [128x256], W_w [256x128] -> bf16 -------------
__global__ __launch_bounds__(256) void prep_w(
    const float* __restrict__ thw, const float* __restrict__ phw,
    const float* __restrict__ gw,  const float* __restrict__ Ww,
    __bf16* __restrict__ wbf)
{
    const int idx  = blockIdx.x * 256 + threadIdx.x;
    const int base = idx * 4;
    const float* src = (base < 32768) ? thw : (base < 65536) ? phw
                     : (base < 98304) ? gw  : Ww;
    const int off = base & 32767;
    f32x4 v = *reinterpret_cast<const f32x4*>(src + off);
    bf16x4 o;
    #pragma unroll
    for (int i = 0; i < 4; ++i) o[i] = (__bf16)v[i];
    *reinterpret_cast<bf16x4*>(wbf + base) = o;
}

// ---------------- Fused projections (r13 structure): transpose x once, loop p=0..2 ----------
// One block per (64-n tile, b). p=0's WL staging is issued BEFORE the transpose so its
// HBM latency hides under the transpose phase. p==2 epilogue writes gBlk (m-group perm).
__global__ __launch_bounds__(256, 1) void proj_fused(
    const float* __restrict__ x, const __bf16* __restrict__ wbf,
    const float* __restrict__ bth, const float* __restrict__ bph,
    const float* __restrict__ bg,
    __bf16* __restrict__ thetaT, __bf16* __restrict__ phiT, __bf16* __restrict__ gBlk)
{
    const int b    = blockIdx.y;
    const int n0   = blockIdx.x * 64;
    const int w    = threadIdx.x >> 6;
    const int lane = threadIdx.x & 63;
    const int lo   = lane & 15;
    const int hi   = lane >> 4;
    const int tr   = threadIdx.x >> 4;      // 0..15
    const int tc   = threadIdx.x & 15;      // 0..15

    __shared__ alignas(16) __bf16 XA[64 * 256];    // 32KB; reused as T[128][66] at p==2
    __shared__ alignas(16) __bf16 WL[128 * 256];   // 64KB
    __shared__ float TF[64][65];                   // 16.6KB transpose scratch

    auto stageWL = [&](int p) {
        #pragma unroll
        for (int u = 0; u < 16; ++u) {
            const int chunk = (w * 16 + u) * 64 + lane;
            const int row   = chunk >> 5;
            const int jb    = (chunk & 31) * 16;
            const int sb    = row * 512 + (jb ^ ((row & 7) << 4));
            GLOAD_LDS16(wbf + p * 32768 + (sb >> 1), &WL[(w * 16 + u) * 512]);
        }
    };

    // issue p=0 weights now; latency hides under the x-transpose below
    stageWL(0);

    // ---- stage x -> XA (transposed, bf16, swizzled), 4 chunks of 64 channels ----
    #pragma unroll 1
    for (int cb = 0; cb < 4; ++cb) {
        if (cb) __syncthreads();
        #pragma unroll
        for (int k = 0; k < 4; ++k) {
            const int cl = k * 16 + tr;
            f32x4 v = *reinterpret_cast<const f32x4*>(
                x + ((size_t)b * 256 + cb * 64 + cl) * 4096 + n0 + tc * 4);
            #pragma unroll
            for (int i = 0; i < 4; ++i) TF[cl][tc * 4 + i] = v[i];
        }
        __syncthreads();
        #pragma unroll
        for (int k = 0; k < 4; ++k) {
            const int nl = k * 16 + tr;
            bf16x4 v;
            #pragma unroll
            for (int i = 0; i < 4; ++i) v[i] = (__bf16)TF[tc * 4 + i][nl];
            const int dst = nl * 512 + ((cb * 128 + tc * 8) ^ ((nl & 7) << 4));
            *reinterpret_cast<bf16x4*>((char*)XA + dst) = v;
        }
    }
    __syncthreads();    // XA ready; barrier also drains p=0's WL loads

    // ---- loop over the three projections ----
    #pragma unroll 1
    for (int p = 0; p < 3; ++p) {
        if (p) {
            __syncthreads();                // WL WAR vs previous MFMA reads
            stageWL(p);
            __syncthreads();
        }

        f32x4 C[8];
        #pragma unroll
        for (int cc = 0; cc < 8; ++cc) C[cc] = f32x4{0.f, 0.f, 0.f, 0.f};

        const int arow = w * 16 + lo;
        #pragma unroll
        for (int kb = 0; kb < 8; ++kb) {
            const int koff = kb * 64 + hi * 16;
            bf16x8 a = *reinterpret_cast<const bf16x8*>(
                (const char*)XA + arow * 512 + (koff ^ ((arow & 7) << 4)));
            bf16x8 bb[8];
            #pragma unroll
            for (int cc = 0; cc < 8; ++cc) {
                const int o = cc * 16 + lo;
                bb[cc] = *reinterpret_cast<const bf16x8*>(
                    (const char*)WL + o * 512 + (koff ^ ((o & 7) << 4)));
            }
            #pragma unroll
            for (int cc = 0; cc < 8; ++cc) C[cc] = mfma16(a, bb[cc], C[cc]);
        }

        const float* bias = (p == 0) ? bth : (p == 1) ? bph : bg;
        if (p < 2) {
            __bf16* out = (p == 0) ? thetaT : phiT;
            const int nbase = n0 + w * 16;
            #pragma unroll
            for (int cc = 0; cc < 8; ++cc) {
                const float bv = bias[cc * 16 + lo];
                #pragma unroll
                for (int r = 0; r < 4; ++r)
                    out[((size_t)b * 4096 + nbase + 4 * hi + r) * 128 + cc * 16 + lo] =
                        (__bf16)(C[cc][r] + bv);
            }
        } else {
            // transpose via LDS (XA dead after last MFMA), write gBlk (m-group perm)
            __syncthreads();
            __bf16* T = &XA[0];                    // T[o][66], 128 x 66
            const int nl0 = w * 16 + 4 * hi;
            #pragma unroll
            for (int cc = 0; cc < 8; ++cc) {
                const float bv = bias[cc * 16 + lo];
                #pragma unroll
                for (int r = 0; r < 4; ++r)
                    T[(cc * 16 + lo) * 66 + nl0 + r] = (__bf16)(C[cc][r] + bv);
            }
            __syncthreads();
            #pragma unroll
            for (int q8 = 0; q8 < 8; ++q8) {
                const int qid = q8 * 256 + threadIdx.x;   // 0..2047
                const int c   = qid >> 4;                 // channel 0..127
                const int nl  = (qid & 15) * 4;
                const int n   = n0 + nl;
                const int mt  = n >> 5;
                const int mm  = n & 31;
                const int g   = mm >> 2;
                const int gp  = (g & 4) | ((g & 1) << 1) | ((g >> 1) & 1);
                bf16x4 v;
                #pragma unroll
                for (int i = 0; i < 4; ++i) v[i] = T[c * 66 + nl + i];
                *reinterpret_cast<bf16x4*>(
                    gBlk + (((size_t)(b * 128 + mt)) * 128 + c) * 32 + (gp << 2)) = v;
            }
        }
    }
}

// ---------------- Flash attention: round-9 winner (45.5us), unchanged -----------------------
template<int NCH>
__global__ __launch_bounds__(256, 3) void attn_kernel(
    const __bf16* __restrict__ thetaT, const __bf16* __restrict__ phiT,
    const __bf16* __restrict__ gBlk, __bf16* __restrict__ yPart,
    float* __restrict__ lPart)
{
    constexpr int SH = (NCH == 8) ? 3 : 2;
    constexpr int NT = (4096 / NCH) / 32;
    const int bid   = blockIdx.x;
    const int chunk = bid & (NCH - 1);
    const int qb    = (bid >> SH) & 31;
    const int b     = bid >> (SH + 5);
    const int w     = threadIdx.x >> 6;
    const int lane  = threadIdx.x & 63;
    const int l31   = lane & 31;
    const int h2    = lane >> 5;
    const int Q0    = qb * 128 + w * 32;
    const int kvbase = chunk * (4096 / NCH);

    __shared__ alignas(16) __bf16 Kt[3][32 * 128];
    __shared__ alignas(16) __bf16 Vt[3][128 * 32];

    bf16x8 qf[8];
    {
        const __bf16* qrow = thetaT + ((size_t)b * 4096 + Q0 + l31) * 128 + h2 * 8;
        #pragma unroll
        for (int ks = 0; ks < 8; ++ks)
            qf[ks] = *reinterpret_cast<const bf16x8*>(qrow + ks * 16);
    }

    f32x16 yacc[4];
    #pragma unroll
    for (int ct = 0; ct < 4; ++ct)
        #pragma unroll
        for (int r = 0; r < 16; ++r) yacc[ct][r] = 0.f;
    float ylrun = 0.f;

    const __bf16* phiB   = phiT + (size_t)b * 4096 * 128;
    const __bf16* gBlk_b = gBlk + (size_t)b * 128 * 4096;

    auto stage = [&](int buf, int t) {
        const int kv = kvbase + t * 32;
        #pragma unroll
        for (int u = 0; u < 2; ++u) {
            const int ii   = w + u * 4;
            const int mrow = ii * 4 + (lane >> 4);
            const int cbl  = ((lane & 15) * 16) ^ ((mrow & 7) << 4);
            const __bf16* src = phiB + ((size_t)(kv + mrow) << 7) + (cbl >> 1);
            GLOAD_LDS16(src, &Kt[buf][ii * 512]);
        }
        const __bf16* vtile = gBlk_b + ((size_t)(kv >> 5) << 12);
        #pragma unroll
        for (int u = 0; u < 2; ++u) {
            const int jj = w + u * 4;
            const int ch = jj * 64 + lane;
            const int c  = ch >> 2;
            const int h  = (ch & 3) ^ ((c >> 1) & 3);
            const __bf16* src = vtile + c * 32 + h * 8;
            GLOAD_LDS16(src, &Vt[buf][jj * 512]);
        }
    };

    stage(0, 0);
    stage(1, 1);

    int ia = 0, ib = 1, ic = 2;
    const int sw = (l31 >> 1) & 3;

    #pragma unroll 1
    for (int t = 0; t < NT; ++t) {
        if (t < NT - 2) {
            stage(ic, t + 2);
            asm volatile("s_waitcnt vmcnt(8)" ::: "memory");
        } else if (t == NT - 2) {
            asm volatile("s_waitcnt vmcnt(4)" ::: "memory");
        } else {
            asm volatile("s_waitcnt vmcnt(0)" ::: "memory");
        }
        __builtin_amdgcn_s_barrier();
        __builtin_amdgcn_sched_barrier(0);

        const char* Kb = (const char*)&Kt[ia][0];
        const char* Vb = (const char*)&Vt[ia][0];

        f32x16 S;
        #pragma unroll
        for (int r = 0; r < 16; ++r) S[r] = 0.f;
        #pragma unroll
        for (int ks = 0; ks < 8; ++ks) {
            bf16x8 ka = *reinterpret_cast<const bf16x8*>(
                Kb + l31 * 256 + ((ks * 32 + h2 * 16) ^ ((l31 & 7) << 4)));
            S = mfma32(ka, qf[ks], S);
        }

        float p[16];
        #pragma unroll
        for (int r = 0; r < 16; ++r) p[r] = __builtin_amdgcn_exp2f(S[r] * L2E);
        float ls = 0.f;
        #pragma unroll
        for (int r = 0; r < 16; ++r) ls += p[r];
        ylrun += ls;
        bf16x8 pa0, pa1;
        #pragma unroll
        for (int e = 0; e < 8; ++e) { pa0[e] = (__bf16)p[e]; pa1[e] = (__bf16)p[8 + e]; }

        #pragma unroll
        for (int ct = 0; ct < 4; ++ct) {
            const int vrow = (ct * 32 + l31) * 64;
            bf16x8 v0 = *reinterpret_cast<const bf16x8*>(Vb + vrow + ((h2 ^ sw) << 4));
            bf16x8 v1 = *reinterpret_cast<const bf16x8*>(Vb + vrow + (((2 + h2) ^ sw) << 4));
            yacc[ct] = mfma32(pa0, v0, yacc[ct]);
            yacc[ct] = mfma32(pa1, v1, yacc[ct]);
        }

        asm volatile("" ::: "memory");
        __builtin_amdgcn_s_barrier();
        __builtin_amdgcn_sched_barrier(0);
        const int tmp = ia; ia = ib; ib = ic; ic = tmp;
    }

    const float ylt = ylrun + __shfl_xor(ylrun, 32);
    const int bc = chunk * 4 + b;
    #pragma unroll
    for (int ct = 0; ct < 4; ++ct)
        #pragma unroll
        for (int r = 0; r < 16; ++r) {
            const int q = Q0 + (r & 3) + 8 * (r >> 2) + 4 * h2;
            yPart[((size_t)bc * 4096 + q) * 128 + ct * 32 + l31] = (__bf16)yacc[ct][r];
        }
    if (h2 == 0)
        lPart[(size_t)bc * 4096 + Q0 + l31] = ylt;
}

// ---------------- wy MFMA: fused chunk-merge + inline linv + deferred normalize + BN stats --
template<int NC>
__global__ __launch_bounds__(256, 1) void wy_mfma(
    const __bf16* __restrict__ yPart, const float* __restrict__ lPart,
    const __bf16* __restrict__ wW, const float* __restrict__ Wb,
    __bf16* __restrict__ Wy, float* __restrict__ pSQ)
{
    const int b    = blockIdx.y;
    const int n0   = blockIdx.x * 64;
    const int w    = threadIdx.x >> 6;
    const int lane = threadIdx.x & 63;
    const int lo   = lane & 15;
    const int hi   = lane >> 4;

    __shared__ alignas(16) __bf16 YL[64 * 128];
    __shared__ alignas(16) __bf16 WL[256 * 128];

    #pragma unroll
    for (int u = 0; u < 16; ++u) {
        const int chunk = (w * 16 + u) * 64 + lane;
        const int row   = chunk >> 4;
        const int jb    = (chunk & 15) * 16;
        const int sb    = row * 256 + (jb ^ ((row & 7) << 4));
        GLOAD_LDS16(wW + (sb >> 1), &WL[(w * 16 + u) * 512]);
    }
    #pragma unroll
    for (int u = 0; u < 4; ++u) {
        const int ch   = u * 256 + threadIdx.x;
        const int row  = ch >> 4;
        const int col8 = ch & 15;
        float acc8[8];
        #pragma unroll
        for (int e = 0; e < 8; ++e) acc8[e] = 0.f;
        #pragma unroll
        for (int c = 0; c < NC; ++c) {
            bf16x8 v = *reinterpret_cast<const bf16x8*>(
                yPart + ((size_t)(c * 4 + b) * 4096 + n0 + row) * 128 + col8 * 8);
            #pragma unroll
            for (int e = 0; e < 8; ++e) acc8[e] += (float)v[e];
        }
        bf16x8 o8;
        #pragma unroll
        for (int e = 0; e < 8; ++e) o8[e] = (__bf16)acc8[e];
        *reinterpret_cast<bf16x8*>(
            (char*)YL + row * 256 + ((col8 * 16) ^ ((row & 7) << 4))) = o8;
    }
    __syncthreads();

    f32x4 C[4][4];
    #pragma unroll
    for (int og = 0; og < 4; ++og)
        #pragma unroll
        for (int ct = 0; ct < 4; ++ct) C[og][ct] = f32x4{0.f, 0.f, 0.f, 0.f};

    #pragma unroll
    for (int kb = 0; kb < 4; ++kb) {
        const int koff = kb * 64 + hi * 16;
        bf16x8 a[4], bb[4];
        #pragma unroll
        for (int og = 0; og < 4; ++og) {
            const int o = w * 64 + og * 16 + lo;
            a[og] = *reinterpret_cast<const bf16x8*>(
                (const char*)WL + o * 256 + (koff ^ ((o & 7) << 4)));
        }
        #pragma unroll
        for (int ct = 0; ct < 4; ++ct) {
            const int nl = ct * 16 + lo;
            bb[ct] = *reinterpret_cast<const bf16x8*>(
                (const char*)YL + nl * 256 + (koff ^ ((nl & 7) << 4)));
        }
        #pragma unroll
        for (int og = 0; og < 4; ++og)
            #pragma unroll
            for (int ct = 0; ct < 4; ++ct)
                C[og][ct] = mfma16(a[og], bb[ct], C[og][ct]);
    }

    float linvv[4];
    #pragma unroll
    for (int ct = 0; ct < 4; ++ct) {
        const int n = b * 4096 + n0 + ct * 16 + lo;
        float s = 0.f;
        #pragma unroll
        for (int c = 0; c < NC; ++c) s += lPart[(size_t)c * 16384 + n];
        linvv[ct] = 1.0f / s;
    }

    const int blk = blockIdx.y * 64 + blockIdx.x;   // 0..255
    #pragma unroll
    for (int og = 0; og < 4; ++og)
        #pragma unroll
        for (int r = 0; r < 4; ++r) {
            const int o  = w * 64 + og * 16 + 4 * hi + r;
            const float bv = Wb[o];
            float s = 0.f, q = 0.f;
            #pragma unroll
            for (int ct = 0; ct < 4; ++ct) {
                const float v = C[og][ct][r] * linvv[ct] + bv;
                Wy[((size_t)b * 256 + o) * 4096 + n0 + ct * 16 + lo] = (__bf16)v;
                s += v; q += v * v;
            }
            #pragma unroll
            for (int off = 1; off <= 8; off <<= 1) {
                s += __shfl_xor(s, off);
                q += __shfl_xor(q, off);
            }
            if (lo == 0) {
                pSQ[blk * 256 + o]         = s;
                pSQ[65536 + blk * 256 + o] = q;
            }
        }
}

// ---------------- stats finalize: reduce 256 partials per channel ---------------------------
__global__ __launch_bounds__(256) void stats_finalize(
    const float* __restrict__ pSQ, const float* __restrict__ gamma,
    const float* __restrict__ beta, float* __restrict__ stats)
{
    const int o = blockIdx.x;
    const int t = threadIdx.x;
    float s = pSQ[t * 256 + o];
    float q = pSQ[65536 + t * 256 + o];
    #pragma unroll
    for (int off = 32; off >= 1; off >>= 1) {
        s += __shfl_down(s, off);
        q += __shfl_down(q, off);
    }
    __shared__ float red[8];
    const int wid = t >> 6;
    if ((t & 63) == 0) { red[wid] = s; red[4 + wid] = q; }
    __syncthreads();
    if (t == 0) {
        const float S = red[0] + red[1] + red[2] + red[3];
        const float Q = red[4] + red[5] + red[6] + red[7];
        const float mean = S * (1.f / 16384.f);
        const float var  = Q * (1.f / 16384.f) - mean * mean;
        const float scl  = gamma[o] * rsqrtf(var + 1e-5f);
        stats[o]       = scl;
        stats[256 + o] = beta[o] - mean * scl;
    }
}

// ---------------- out = Wy(bf16)*scale + shift + x ------------------------------------------
__global__ __launch_bounds__(256) void final_kernel(
    const __bf16* __restrict__ Wy, const float* __restrict__ x,
    const float* __restrict__ stats, float* __restrict__ out)
{
    const int idx = blockIdx.x * 256 + threadIdx.x;
    const int o   = (idx >> 10) & 255;
    bf16x4 wyb = *reinterpret_cast<const bf16x4*>(Wy + (size_t)idx * 4);
    f32x4 xv = *reinterpret_cast<const f32x4*>(x + (size_t)idx * 4);
    const float scl = stats[o], sh = stats[256 + o];
    f32x4 res;
    #pragma unroll
    for (int i = 0; i < 4; ++i) res[i] = (float)wyb[i] * scl + sh + xv[i];
    *reinterpret_cast<f32x4*>(out + (size_t)idx * 4) = res;
}

extern "C" void kernel_launch(void* const* d_in, const int* in_sizes, int n_in,
                              void* d_out, int out_size, void* d_ws, size_t ws_size,
                              hipStream_t stream)
{
    const float* x    = (const float*)d_in[0];
    const float* g_w  = (const float*)d_in[1];
    const float* g_b  = (const float*)d_in[2];
    const float* th_w = (const float*)d_in[3];
    const float* th_b = (const float*)d_in[4];
    const float* ph_w = (const float*)d_in[5];
    const float* ph_b = (const float*)d_in[6];
    const float* W_w  = (const float*)d_in[7];
    const float* W_b  = (const float*)d_in[8];
    const float* bn_g = (const float*)d_in[9];
    const float* bn_b = (const float*)d_in[10];
    float* out = (float*)d_out;

    // Workspace phases:
    //   proj:  thetaT@0 (4M) | phiT@4M (4M) | gBlk@8M (4M)
    //   attn:  reads thetaT/phiT/gBlk; yPart@12M (32M big / 16M small)
    //   wy:    reads yPart+lPart; Wy(bf16)@0 (8M over dead thetaT/phiT); pSQ@8M (512K)
    //   tail:  lPart | wbf | stats @44M (big) / @28M (small)
    char* ws = (char*)d_ws;
    const size_t MB = 1u << 20;
    __bf16* thetaT = (__bf16*)(ws);
    __bf16* phiT   = (__bf16*)(ws + 4 * MB);
    __bf16* gBlk   = (__bf16*)(ws + 8 * MB);
    __bf16* yPart  = (__bf16*)(ws + 12 * MB);
    __bf16* Wy     = (__bf16*)(ws);
    float*  pSQ    = (float*) (ws + 8 * MB);

    const bool big = ws_size >= 46926848ull;
    const size_t tail = big ? 44 * MB : 28 * MB;
    float*  lPart = (float*) (ws + tail);
    __bf16* wbf   = (__bf16*)(ws + tail + (big ? 524288 : 262144));
    float*  stats = (float*) (ws + tail + (big ? 786432 : 524288));

    prep_w<<<dim3(128), 256, 0, stream>>>(th_w, ph_w, g_w, W_w, wbf);
    proj_fused<<<dim3(64, 4), 256, 0, stream>>>(
        x, wbf, th_b, ph_b, g_b, thetaT, phiT, gBlk);
    if (big) {
        attn_kernel<8><<<dim3(1024), 256, 0, stream>>>(thetaT, phiT, gBlk, yPart, lPart);
        wy_mfma<8><<<dim3(64, 4), 256, 0, stream>>>(yPart, lPart, wbf + 98304, W_b, Wy, pSQ);
    } else {
        attn_kernel<4><<<dim3(512), 256, 0, stream>>>(thetaT, phiT, gBlk, yPart, lPart);
        wy_mfma<4><<<dim3(64, 4), 256, 0, stream>>>(yPart, lPart, wbf + 98304, W_b, Wy, pSQ);
    }
    stats_finalize<<<dim3(256), 256, 0, stream>>>(pSQ, bn_g, bn_b, stats);
    final_kernel<<<dim3(4096), 256, 0, stream>>>(Wy, x, stats, out);
}

// Round 16
// 86.605 us; speedup vs baseline: 1.1905x; 1.0386x over previous
//
#include <hip/hip_runtime.h>
#include <hip/hip_bf16.h>

typedef __attribute__((ext_vector_type(8))) __bf16 bf16x8;
typedef __attribute__((ext_vector_type(4))) __bf16 bf16x4;
typedef __attribute__((ext_vector_type(4))) float  f32x4;
typedef __attribute__((ext_vector_type(16))) float f32x16;

#define L2E 1.44269504088896340736f

static __device__ __forceinline__ f32x4 mfma16(bf16x8 a, bf16x8 b, f32x4 c) {
    return __builtin_amdgcn_mfma_f32_16x16x32_bf16(a, b, c, 0, 0, 0);
}
static __device__ __forceinline__ f32x16 mfma32(bf16x8 a, bf16x8 b, f32x16 c) {
    return __builtin_amdgcn_mfma_f32_32x32x16_bf16(a, b, c, 0, 0, 0);
}

#define GLOAD_LDS16(gsrc, ldst)                                                \
    __builtin_amdgcn_global_load_lds(                                          \
        (const __attribute__((address_space(1))) unsigned int*)(gsrc),         \
        (__attribute__((address_space(3))) unsigned int*)(ldst), 16, 0, 0)

// ---------------- Weight prep: th_w, ph_w, g_w [128x256], W_w [256x128] -> bf16 -------------
__global__ __launch_bounds__(256) void prep_w(
    const float* __restrict__ thw, const float* __restrict__ phw,
    const float* __restrict__ gw,  const float* __restrict__ Ww,
    __bf16* __restrict__ wbf)
{
    const int idx  = blockIdx.x * 256 + threadIdx.x;
    const int base = idx * 4;
    const float* src = (base < 32768) ? thw : (base < 65536) ? phw
                     : (base < 98304) ? gw  : Ww;
    const int off = base & 32767;
    f32x4 v = *reinterpret_cast<const f32x4*>(src + off);
    bf16x4 o;
    #pragma unroll
    for (int i = 0; i < 4; ++i) o[i] = (__bf16)v[i];
    *reinterpret_cast<bf16x4*>(wbf + base) = o;
}

// ---------------- Fused projections: transpose x once, loop p=0..2 --------------------------
__global__ __launch_bounds__(256, 1) void proj_fused(
    const float* __restrict__ x, const __bf16* __restrict__ wbf,
    const float* __restrict__ bth, const float* __restrict__ bph,
    const float* __restrict__ bg,
    __bf16* __restrict__ thetaT, __bf16* __restrict__ phiT, __bf16* __restrict__ gBlk)
{
    const int b    = blockIdx.y;
    const int n0   = blockIdx.x * 64;
    const int w    = threadIdx.x >> 6;
    const int lane = threadIdx.x & 63;
    const int lo   = lane & 15;
    const int hi   = lane >> 4;
    const int tr   = threadIdx.x >> 4;
    const int tc   = threadIdx.x & 15;

    __shared__ alignas(16) __bf16 XA[64 * 256];
    __shared__ alignas(16) __bf16 WL[128 * 256];
    __shared__ float TF[64][65];

    auto stageWL = [&](int p) {
        #pragma unroll
        for (int u = 0; u < 16; ++u) {
            const int chunk = (w * 16 + u) * 64 + lane;
            const int row   = chunk >> 5;
            const int jb    = (chunk & 31) * 16;
            const int sb    = row * 512 + (jb ^ ((row & 7) << 4));
            GLOAD_LDS16(wbf + p * 32768 + (sb >> 1), &WL[(w * 16 + u) * 512]);
        }
    };

    stageWL(0);

    #pragma unroll 1
    for (int cb = 0; cb < 4; ++cb) {
        if (cb) __syncthreads();
        #pragma unroll
        for (int k = 0; k < 4; ++k) {
            const int cl = k * 16 + tr;
            f32x4 v = *reinterpret_cast<const f32x4*>(
                x + ((size_t)b * 256 + cb * 64 + cl) * 4096 + n0 + tc * 4);
            #pragma unroll
            for (int i = 0; i < 4; ++i) TF[cl][tc * 4 + i] = v[i];
        }
        __syncthreads();
        #pragma unroll
        for (int k = 0; k < 4; ++k) {
            const int nl = k * 16 + tr;
            bf16x4 v;
            #pragma unroll
            for (int i = 0; i < 4; ++i) v[i] = (__bf16)TF[tc * 4 + i][nl];
            const int dst = nl * 512 + ((cb * 128 + tc * 8) ^ ((nl & 7) << 4));
            *reinterpret_cast<bf16x4*>((char*)XA + dst) = v;
        }
    }
    __syncthreads();

    #pragma unroll 1
    for (int p = 0; p < 3; ++p) {
        if (p) {
            __syncthreads();
            stageWL(p);
            __syncthreads();
        }

        f32x4 C[8];
        #pragma unroll
        for (int cc = 0; cc < 8; ++cc) C[cc] = f32x4{0.f, 0.f, 0.f, 0.f};

        const int arow = w * 16 + lo;
        #pragma unroll
        for (int kb = 0; kb < 8; ++kb) {
            const int koff = kb * 64 + hi * 16;
            bf16x8 a = *reinterpret_cast<const bf16x8*>(
                (const char*)XA + arow * 512 + (koff ^ ((arow & 7) << 4)));
            bf16x8 bb[8];
            #pragma unroll
            for (int cc = 0; cc < 8; ++cc) {
                const int o = cc * 16 + lo;
                bb[cc] = *reinterpret_cast<const bf16x8*>(
                    (const char*)WL + o * 512 + (koff ^ ((o & 7) << 4)));
            }
            #pragma unroll
            for (int cc = 0; cc < 8; ++cc) C[cc] = mfma16(a, bb[cc], C[cc]);
        }

        const float* bias = (p == 0) ? bth : (p == 1) ? bph : bg;
        if (p < 2) {
            __bf16* out = (p == 0) ? thetaT : phiT;
            const int nbase = n0 + w * 16;
            #pragma unroll
            for (int cc = 0; cc < 8; ++cc) {
                const float bv = bias[cc * 16 + lo];
                #pragma unroll
                for (int r = 0; r < 4; ++r)
                    out[((size_t)b * 4096 + nbase + 4 * hi + r) * 128 + cc * 16 + lo] =
                        (__bf16)(C[cc][r] + bv);
            }
        } else {
            __syncthreads();
            __bf16* T = &XA[0];
            const int nl0 = w * 16 + 4 * hi;
            #pragma unroll
            for (int cc = 0; cc < 8; ++cc) {
                const float bv = bias[cc * 16 + lo];
                #pragma unroll
                for (int r = 0; r < 4; ++r)
                    T[(cc * 16 + lo) * 66 + nl0 + r] = (__bf16)(C[cc][r] + bv);
            }
            __syncthreads();
            #pragma unroll
            for (int q8 = 0; q8 < 8; ++q8) {
                const int qid = q8 * 256 + threadIdx.x;
                const int c   = qid >> 4;
                const int nl  = (qid & 15) * 4;
                const int n   = n0 + nl;
                const int mt  = n >> 5;
                const int mm  = n & 31;
                const int g   = mm >> 2;
                const int gp  = (g & 4) | ((g & 1) << 1) | ((g >> 1) & 1);
                bf16x4 v;
                #pragma unroll
                for (int i = 0; i < 4; ++i) v[i] = T[c * 66 + nl + i];
                *reinterpret_cast<bf16x4*>(
                    gBlk + (((size_t)(b * 128 + mt)) * 128 + c) * 32 + (gp << 2)) = v;
            }
        }
    }
}

// ---------------- Flash attention: round-9 winner, NCH=4 (uniform 2 blocks/CU) --------------
template<int NCH>
__global__ __launch_bounds__(256, 3) void attn_kernel(
    const __bf16* __restrict__ thetaT, const __bf16* __restrict__ phiT,
    const __bf16* __restrict__ gBlk, __bf16* __restrict__ yPart,
    float* __restrict__ lPart)
{
    constexpr int SH = (NCH == 8) ? 3 : 2;
    constexpr int NT = (4096 / NCH) / 32;
    const int bid   = blockIdx.x;
    const int chunk = bid & (NCH - 1);
    const int qb    = (bid >> SH) & 31;
    const int b     = bid >> (SH + 5);
    const int w     = threadIdx.x >> 6;
    const int lane  = threadIdx.x & 63;
    const int l31   = lane & 31;
    const int h2    = lane >> 5;
    const int Q0    = qb * 128 + w * 32;
    const int kvbase = chunk * (4096 / NCH);

    __shared__ alignas(16) __bf16 Kt[3][32 * 128];
    __shared__ alignas(16) __bf16 Vt[3][128 * 32];

    bf16x8 qf[8];
    {
        const __bf16* qrow = thetaT + ((size_t)b * 4096 + Q0 + l31) * 128 + h2 * 8;
        #pragma unroll
        for (int ks = 0; ks < 8; ++ks)
            qf[ks] = *reinterpret_cast<const bf16x8*>(qrow + ks * 16);
    }

    f32x16 yacc[4];
    #pragma unroll
    for (int ct = 0; ct < 4; ++ct)
        #pragma unroll
        for (int r = 0; r < 16; ++r) yacc[ct][r] = 0.f;
    float ylrun = 0.f;

    const __bf16* phiB   = phiT + (size_t)b * 4096 * 128;
    const __bf16* gBlk_b = gBlk + (size_t)b * 128 * 4096;

    auto stage = [&](int buf, int t) {
        const int kv = kvbase + t * 32;
        #pragma unroll
        for (int u = 0; u < 2; ++u) {
            const int ii   = w + u * 4;
            const int mrow = ii * 4 + (lane >> 4);
            const int cbl  = ((lane & 15) * 16) ^ ((mrow & 7) << 4);
            const __bf16* src = phiB + ((size_t)(kv + mrow) << 7) + (cbl >> 1);
            GLOAD_LDS16(src, &Kt[buf][ii * 512]);
        }
        const __bf16* vtile = gBlk_b + ((size_t)(kv >> 5) << 12);
        #pragma unroll
        for (int u = 0; u < 2; ++u) {
            const int jj = w + u * 4;
            const int ch = jj * 64 + lane;
            const int c  = ch >> 2;
            const int h  = (ch & 3) ^ ((c >> 1) & 3);
            const __bf16* src = vtile + c * 32 + h * 8;
            GLOAD_LDS16(src, &Vt[buf][jj * 512]);
        }
    };

    stage(0, 0);
    stage(1, 1);

    int ia = 0, ib = 1, ic = 2;
    const int sw = (l31 >> 1) & 3;

    #pragma unroll 1
    for (int t = 0; t < NT; ++t) {
        if (t < NT - 2) {
            stage(ic, t + 2);
            asm volatile("s_waitcnt vmcnt(8)" ::: "memory");
        } else if (t == NT - 2) {
            asm volatile("s_waitcnt vmcnt(4)" ::: "memory");
        } else {
            asm volatile("s_waitcnt vmcnt(0)" ::: "memory");
        }
        __builtin_amdgcn_s_barrier();
        __builtin_amdgcn_sched_barrier(0);

        const char* Kb = (const char*)&Kt[ia][0];
        const char* Vb = (const char*)&Vt[ia][0];

        f32x16 S;
        #pragma unroll
        for (int r = 0; r < 16; ++r) S[r] = 0.f;
        #pragma unroll
        for (int ks = 0; ks < 8; ++ks) {
            bf16x8 ka = *reinterpret_cast<const bf16x8*>(
                Kb + l31 * 256 + ((ks * 32 + h2 * 16) ^ ((l31 & 7) << 4)));
            S = mfma32(ka, qf[ks], S);
        }

        float p[16];
        #pragma unroll
        for (int r = 0; r < 16; ++r) p[r] = __builtin_amdgcn_exp2f(S[r] * L2E);
        float ls = 0.f;
        #pragma unroll
        for (int r = 0; r < 16; ++r) ls += p[r];
        ylrun += ls;
        bf16x8 pa0, pa1;
        #pragma unroll
        for (int e = 0; e < 8; ++e) { pa0[e] = (__bf16)p[e]; pa1[e] = (__bf16)p[8 + e]; }

        #pragma unroll
        for (int ct = 0; ct < 4; ++ct) {
            const int vrow = (ct * 32 + l31) * 64;
            bf16x8 v0 = *reinterpret_cast<const bf16x8*>(Vb + vrow + ((h2 ^ sw) << 4));
            bf16x8 v1 = *reinterpret_cast<const bf16x8*>(Vb + vrow + (((2 + h2) ^ sw) << 4));
            yacc[ct] = mfma32(pa0, v0, yacc[ct]);
            yacc[ct] = mfma32(pa1, v1, yacc[ct]);
        }

        asm volatile("" ::: "memory");
        __builtin_amdgcn_s_barrier();
        __builtin_amdgcn_sched_barrier(0);
        const int tmp = ia; ia = ib; ib = ic; ic = tmp;
    }

    const float ylt = ylrun + __shfl_xor(ylrun, 32);
    const int bc = chunk * 4 + b;
    #pragma unroll
    for (int ct = 0; ct < 4; ++ct)
        #pragma unroll
        for (int r = 0; r < 16; ++r) {
            const int q = Q0 + (r & 3) + 8 * (r >> 2) + 4 * h2;
            yPart[((size_t)bc * 4096 + q) * 128 + ct * 32 + l31] = (__bf16)yacc[ct][r];
        }
    if (h2 == 0)
        lPart[(size_t)bc * 4096 + Q0 + l31] = ylt;
}

// ---------------- wy MFMA: fused chunk-merge + inline linv + deferred normalize + BN stats --
template<int NC>
__global__ __launch_bounds__(256, 1) void wy_mfma(
    const __bf16* __restrict__ yPart, const float* __restrict__ lPart,
    const __bf16* __restrict__ wW, const float* __restrict__ Wb,
    __bf16* __restrict__ Wy, float* __restrict__ pSQ)
{
    const int b    = blockIdx.y;
    const int n0   = blockIdx.x * 64;
    const int w    = threadIdx.x >> 6;
    const int lane = threadIdx.x & 63;
    const int lo   = lane & 15;
    const int hi   = lane >> 4;

    __shared__ alignas(16) __bf16 YL[64 * 128];
    __shared__ alignas(16) __bf16 WL[256 * 128];

    #pragma unroll
    for (int u = 0; u < 16; ++u) {
        const int chunk = (w * 16 + u) * 64 + lane;
        const int row   = chunk >> 4;
        const int jb    = (chunk & 15) * 16;
        const int sb    = row * 256 + (jb ^ ((row & 7) << 4));
        GLOAD_LDS16(wW + (sb >> 1), &WL[(w * 16 + u) * 512]);
    }
    #pragma unroll
    for (int u = 0; u < 4; ++u) {
        const int ch   = u * 256 + threadIdx.x;
        const int row  = ch >> 4;
        const int col8 = ch & 15;
        float acc8[8];
        #pragma unroll
        for (int e = 0; e < 8; ++e) acc8[e] = 0.f;
        #pragma unroll
        for (int c = 0; c < NC; ++c) {
            bf16x8 v = *reinterpret_cast<const bf16x8*>(
                yPart + ((size_t)(c * 4 + b) * 4096 + n0 + row) * 128 + col8 * 8);
            #pragma unroll
            for (int e = 0; e < 8; ++e) acc8[e] += (float)v[e];
        }
        bf16x8 o8;
        #pragma unroll
        for (int e = 0; e < 8; ++e) o8[e] = (__bf16)acc8[e];
        *reinterpret_cast<bf16x8*>(
            (char*)YL + row * 256 + ((col8 * 16) ^ ((row & 7) << 4))) = o8;
    }
    __syncthreads();

    f32x4 C[4][4];
    #pragma unroll
    for (int og = 0; og < 4; ++og)
        #pragma unroll
        for (int ct = 0; ct < 4; ++ct) C[og][ct] = f32x4{0.f, 0.f, 0.f, 0.f};

    #pragma unroll
    for (int kb = 0; kb < 4; ++kb) {
        const int koff = kb * 64 + hi * 16;
        bf16x8 a[4], bb[4];
        #pragma unroll
        for (int og = 0; og < 4; ++og) {
            const int o = w * 64 + og * 16 + lo;
            a[og] = *reinterpret_cast<const bf16x8*>(
                (const char*)WL + o * 256 + (koff ^ ((o & 7) << 4)));
        }
        #pragma unroll
        for (int ct = 0; ct < 4; ++ct) {
            const int nl = ct * 16 + lo;
            bb[ct] = *reinterpret_cast<const bf16x8*>(
                (const char*)YL + nl * 256 + (koff ^ ((nl & 7) << 4)));
        }
        #pragma unroll
        for (int og = 0; og < 4; ++og)
            #pragma unroll
            for (int ct = 0; ct < 4; ++ct)
                C[og][ct] = mfma16(a[og], bb[ct], C[og][ct]);
    }

    float linvv[4];
    #pragma unroll
    for (int ct = 0; ct < 4; ++ct) {
        const int n = b * 4096 + n0 + ct * 16 + lo;
        float s = 0.f;
        #pragma unroll
        for (int c = 0; c < NC; ++c) s += lPart[(size_t)c * 16384 + n];
        linvv[ct] = 1.0f / s;
    }

    const int blk = blockIdx.y * 64 + blockIdx.x;
    #pragma unroll
    for (int og = 0; og < 4; ++og)
        #pragma unroll
        for (int r = 0; r < 4; ++r) {
            const int o  = w * 64 + og * 16 + 4 * hi + r;
            const float bv = Wb[o];
            float s = 0.f, q = 0.f;
            #pragma unroll
            for (int ct = 0; ct < 4; ++ct) {
                const float v = C[og][ct][r] * linvv[ct] + bv;
                Wy[((size_t)b * 256 + o) * 4096 + n0 + ct * 16 + lo] = (__bf16)v;
                s += v; q += v * v;
            }
            #pragma unroll
            for (int off = 1; off <= 8; off <<= 1) {
                s += __shfl_xor(s, off);
                q += __shfl_xor(q, off);
            }
            if (lo == 0) {
                pSQ[blk * 256 + o]         = s;
                pSQ[65536 + blk * 256 + o] = q;
            }
        }
}

// ---------------- stats finalize: reduce 256 partials per channel ---------------------------
__global__ __launch_bounds__(256) void stats_finalize(
    const float* __restrict__ pSQ, const float* __restrict__ gamma,
    const float* __restrict__ beta, float* __restrict__ stats)
{
    const int o = blockIdx.x;
    const int t = threadIdx.x;
    float s = pSQ[t * 256 + o];
    float q = pSQ[65536 + t * 256 + o];
    #pragma unroll
    for (int off = 32; off >= 1; off >>= 1) {
        s += __shfl_down(s, off);
        q += __shfl_down(q, off);
    }
    __shared__ float red[8];
    const int wid = t >> 6;
    if ((t & 63) == 0) { red[wid] = s; red[4 + wid] = q; }
    __syncthreads();
    if (t == 0) {
        const float S = red[0] + red[1] + red[2] + red[3];
        const float Q = red[4] + red[5] + red[6] + red[7];
        const float mean = S * (1.f / 16384.f);
        const float var  = Q * (1.f / 16384.f) - mean * mean;
        const float scl  = gamma[o] * rsqrtf(var + 1e-5f);
        stats[o]       = scl;
        stats[256 + o] = beta[o] - mean * scl;
    }
}

// ---------------- out = Wy(bf16)*scale + shift + x ------------------------------------------
__global__ __launch_bounds__(256) void final_kernel(
    const __bf16* __restrict__ Wy, const float* __restrict__ x,
    const float* __restrict__ stats, float* __restrict__ out)
{
    const int idx = blockIdx.x * 256 + threadIdx.x;
    const int o   = (idx >> 10) & 255;
    bf16x4 wyb = *reinterpret_cast<const bf16x4*>(Wy + (size_t)idx * 4);
    f32x4 xv = *reinterpret_cast<const f32x4*>(x + (size_t)idx * 4);
    const float scl = stats[o], sh = stats[256 + o];
    f32x4 res;
    #pragma unroll
    for (int i = 0; i < 4; ++i) res[i] = (float)wyb[i] * scl + sh + xv[i];
    *reinterpret_cast<f32x4*>(out + (size_t)idx * 4) = res;
}

extern "C" void kernel_launch(void* const* d_in, const int* in_sizes, int n_in,
                              void* d_out, int out_size, void* d_ws, size_t ws_size,
                              hipStream_t stream)
{
    const float* x    = (const float*)d_in[0];
    const float* g_w  = (const float*)d_in[1];
    const float* g_b  = (const float*)d_in[2];
    const float* th_w = (const float*)d_in[3];
    const float* th_b = (const float*)d_in[4];
    const float* ph_w = (const float*)d_in[5];
    const float* ph_b = (const float*)d_in[6];
    const float* W_w  = (const float*)d_in[7];
    const float* W_b  = (const float*)d_in[8];
    const float* bn_g = (const float*)d_in[9];
    const float* bn_b = (const float*)d_in[10];
    float* out = (float*)d_out;

    // Workspace phases (NCH=4 always; yPart 16M fits the small layout):
    //   proj:  thetaT@0 (4M) | phiT@4M (4M) | gBlk@8M (4M)
    //   attn:  yPart@12M (16M)
    //   wy:    Wy(bf16)@0 (8M over dead thetaT/phiT); pSQ@8M (512K over dead gBlk)
    //   tail:  lPart(256K) | wbf(256K) | stats @28M
    char* ws = (char*)d_ws;
    const size_t MB = 1u << 20;
    __bf16* thetaT = (__bf16*)(ws);
    __bf16* phiT   = (__bf16*)(ws + 4 * MB);
    __bf16* gBlk   = (__bf16*)(ws + 8 * MB);
    __bf16* yPart  = (__bf16*)(ws + 12 * MB);
    __bf16* Wy     = (__bf16*)(ws);
    float*  pSQ    = (float*) (ws + 8 * MB);

    const size_t tail = 28 * MB;
    float*  lPart = (float*) (ws + tail);
    __bf16* wbf   = (__bf16*)(ws + tail + 262144);
    float*  stats = (float*) (ws + tail + 524288);

    prep_w<<<dim3(128), 256, 0, stream>>>(th_w, ph_w, g_w, W_w, wbf);
    proj_fused<<<dim3(64, 4), 256, 0, stream>>>(
        x, wbf, th_b, ph_b, g_b, thetaT, phiT, gBlk);
    attn_kernel<4><<<dim3(512), 256, 0, stream>>>(thetaT, phiT, gBlk, yPart, lPart);
    wy_mfma<4><<<dim3(64, 4), 256, 0, stream>>>(yPart, lPart, wbf + 98304, W_b, Wy, pSQ);
    stats_finalize<<<dim3(256), 256, 0, stream>>>(pSQ, bn_g, bn_b, stats);
    final_kernel<<<dim3(4096), 256, 0, stream>>>(Wy, x, stats, out);
}